// Round 13
// baseline (1683.591 us; speedup 1.0000x reference)
//
#include <hip/hip_runtime.h>

// SentimentLSTM: B=64, T=512, E=128, H=256, V=100000, O=1
// outputs: sig_out[64], hT[1,64,256], cT[1,64,256] -> 32832 f32
//
// k_rec: 4 blocks, ZERO cross-block communication.
//   Block o: batches o*16..+15, ALL 256 units. W_hh quantized to i8
//   (per-row scale, 256 KB = 128 VGPRs/lane), resident in registers.
//   Per step: 32x mfma_i32_16x16x64_i8 per wave (K=256), gates = bf16 gx
//   (biases folded, exact) + i32 * (sW_row * sH_step); h requantized to i8
//   with dynamic per-step block scale (block max |h|) into LDS dbuf.
//   Head (h . weff -> sigmoid -> mean) fused. No exchange, no polls, no
//   atomics, no memsets.
//
// ws layout:
//   gx4  bf16 [T][4 o][8 w][64 lane][32 v]   67,108,864 B  (lane-major)
//   weff f32  [257]                                1,028 B

#define BATCH 64
#define TSTEPS 512
#define EDIM 128
#define HDIM 256
#define G4H 1024

typedef short bf16x8 __attribute__((ext_vector_type(8)));
typedef short bf16x4 __attribute__((ext_vector_type(4)));
typedef float f32x4 __attribute__((ext_vector_type(4)));
typedef int i32x4 __attribute__((ext_vector_type(4)));

__device__ __forceinline__ unsigned short f2bf(float f) {
  unsigned u = __builtin_bit_cast(unsigned, f);
  return (unsigned short)((u + 0x7fffu + ((u >> 16) & 1u)) >> 16);
}
__device__ __forceinline__ float bf2f(unsigned short h) {
  unsigned u = ((unsigned)h) << 16;
  return __builtin_bit_cast(float, u);
}
__device__ __forceinline__ unsigned pk2(float a, float b) {
  return (unsigned)f2bf(a) | ((unsigned)f2bf(b) << 16);
}
__device__ __forceinline__ float fsig(float x) {
  return __builtin_amdgcn_rcpf(1.f + __expf(-x));
}
__device__ __forceinline__ float ftanh(float x) {
  return 1.f - 2.f * __builtin_amdgcn_rcpf(__expf(2.f * x) + 1.f);
}
__device__ __forceinline__ bf16x8 ldfrag(const unsigned short* p) {
  bf16x4 a = *(const bf16x4*)p;
  bf16x4 b = *(const bf16x4*)(p + 16);
  return __builtin_shufflevector(a, b, 0, 1, 2, 3, 4, 5, 6, 7);
}
__device__ __forceinline__ int q8(float v, float qs) {
  float r = __builtin_rintf(v * qs);
  r = fmaxf(-127.f, fminf(127.f, r));
  return (int)r;
}

// ---------------- K1: gx4 = emb[x] @ W_ih^T + (b_ih + b_hh), lane-major -----
__global__ __launch_bounds__(256) void k_gx(const int* __restrict__ x,
                                            const float* __restrict__ emb,
                                            const float* __restrict__ Wih,
                                            const float* __restrict__ bih,
                                            const float* __restrict__ bhh,
                                            unsigned short* __restrict__ gx4) {
  const int t = blockIdx.x;
  const int g0 = blockIdx.y * 64;
  const int tid = threadIdx.x;
  __shared__ unsigned short Al[64 * 136];
  __shared__ unsigned short Bl[64 * 136];
  __shared__ int tok[64];
  if (tid < 64) tok[tid] = x[tid * TSTEPS + t];
  __syncthreads();
  {
    const int r = tid >> 2, c0 = (tid & 3) * 32;
    const float* asrc = emb + (size_t)tok[r] * EDIM + c0;
    const float* bsrc = Wih + (size_t)(g0 + r) * EDIM + c0;
#pragma unroll
    for (int s = 0; s < 32; s += 8) {
      float4 a0 = *(const float4*)(asrc + s);
      float4 a1 = *(const float4*)(asrc + s + 4);
      uint4 pa = {pk2(a0.x, a0.y), pk2(a0.z, a0.w), pk2(a1.x, a1.y), pk2(a1.z, a1.w)};
      *(uint4*)&Al[r * 136 + c0 + s] = pa;
      float4 b0 = *(const float4*)(bsrc + s);
      float4 b1 = *(const float4*)(bsrc + s + 4);
      uint4 pb = {pk2(b0.x, b0.y), pk2(b0.z, b0.w), pk2(b1.x, b1.y), pk2(b1.z, b1.w)};
      *(uint4*)&Bl[r * 136 + c0 + s] = pb;
    }
  }
  __syncthreads();
  const int lane = tid & 63, w = tid >> 6;
  const int lo = lane & 15, hi = lane >> 4;
  const int mb = (w & 1) * 32, nb = (w >> 1) * 32;
  f32x4 acc[2][2];
#pragma unroll
  for (int jj = 0; jj < 2; ++jj) {
    const int col = g0 + nb + jj * 16 + lo;
    float bv = bih[col] + bhh[col];
    acc[0][jj] = (f32x4){bv, bv, bv, bv};
    acc[1][jj] = acc[0][jj];
  }
#pragma unroll
  for (int kk = 0; kk < 4; ++kk) {
    bf16x8 af0 = ldfrag(&Al[(mb + lo) * 136 + kk * 32 + hi * 4]);
    bf16x8 af1 = ldfrag(&Al[(mb + 16 + lo) * 136 + kk * 32 + hi * 4]);
    bf16x8 bf0 = ldfrag(&Bl[(nb + lo) * 136 + kk * 32 + hi * 4]);
    bf16x8 bf1 = ldfrag(&Bl[(nb + 16 + lo) * 136 + kk * 32 + hi * 4]);
    acc[0][0] = __builtin_amdgcn_mfma_f32_16x16x32_bf16(af0, bf0, acc[0][0], 0, 0, 0);
    acc[0][1] = __builtin_amdgcn_mfma_f32_16x16x32_bf16(af0, bf1, acc[0][1], 0, 0, 0);
    acc[1][0] = __builtin_amdgcn_mfma_f32_16x16x32_bf16(af1, bf0, acc[1][0], 0, 0, 0);
    acc[1][1] = __builtin_amdgcn_mfma_f32_16x16x32_bf16(af1, bf1, acc[1][1], 0, 0, 0);
  }
  // gx4 idx = (((t*4 + o)*8 + w4)*64 + (hi*16+lo))*32 + (g*2+t2)*4 + r
#pragma unroll
  for (int i = 0; i < 2; ++i)
#pragma unroll
    for (int jj = 0; jj < 2; ++jj) {
      const int o = (w & 1) * 2 + i;          // m>>4
      const int col = g0 + nb + jj * 16 + lo;
      const int g = col >> 8, rem = col & 255;
      const int w4 = rem >> 5, t2 = (rem >> 4) & 1;
      size_t idx = ((((size_t)t * 4 + o) * 8 + w4) * 64 + (hi * 16 + lo)) * 32 +
                   (g * 2 + t2) * 4;
      unsigned long long val =
          (unsigned long long)pk2(acc[i][jj][0], acc[i][jj][1]) |
          ((unsigned long long)pk2(acc[i][jj][2], acc[i][jj][3]) << 32);
      *(unsigned long long*)&gx4[idx] = val;
    }
}

// ---------------- K2: recurrence, W_hh i8-resident, no exchange -------------
__global__ __launch_bounds__(512) void k_rec(const unsigned short* __restrict__ gx4,
                                             const float* __restrict__ Whh,
                                             const float* __restrict__ weff,
                                             float* __restrict__ out) {
  const int tid = threadIdx.x;
  const int blk = blockIdx.x;              // 0..3 : batches blk*16..+15
  const int lane = tid & 63, w = tid >> 6;
  const int lo = lane & 15, hi = lane >> 4;
  // h8: i8 h, [granule u>>4][batch][e u&15], granule stride 272 B, dbuf
  __shared__ unsigned char h8[2][16 * 272];
  __shared__ float mxl[8];
  // ---- W quantize: rows g*256 + w*32 + t2*16 + lo; frag k = kk*64+hi*16+e
  i32x4 wq[4][2][4];
  float sW[4][2];
#pragma unroll
  for (int g = 0; g < 4; ++g)
#pragma unroll
    for (int t2 = 0; t2 < 2; ++t2) {
      const float* wr = Whh + (size_t)(g * 256 + w * 32 + t2 * 16 + lo) * HDIM;
      float m = 0.f;
#pragma unroll 16
      for (int e = 0; e < 64; ++e) {
        float4 v = *(const float4*)(wr + e * 4);
        m = fmaxf(m, fmaxf(fmaxf(fabsf(v.x), fabsf(v.y)),
                           fmaxf(fabsf(v.z), fabsf(v.w))));
      }
      m = fmaxf(m, 1e-20f);
      sW[g][t2] = m * (1.f / 127.f);
      const float qs = 127.f / m;
#pragma unroll
      for (int kk = 0; kk < 4; ++kk) {
        int wd[4];
#pragma unroll
        for (int u2 = 0; u2 < 4; ++u2) {
          float4 v = *(const float4*)(wr + kk * 64 + hi * 16 + u2 * 4);
          int b0 = q8(v.x, qs), b1 = q8(v.y, qs), b2 = q8(v.z, qs), b3 = q8(v.w, qs);
          wd[u2] = (b0 & 255) | ((b1 & 255) << 8) | ((b2 & 255) << 16) | ((b3 & 255) << 24);
        }
        wq[g][t2][kk] = (i32x4){wd[0], wd[1], wd[2], wd[3]};
      }
    }
  // ---- head roles & weff frag
  const int hb_b = tid >> 5, hsub = tid & 31;
  const int hgr = hsub >> 1, heh = (hsub & 1) * 8;
  float wv8[8];
#pragma unroll
  for (int e = 0; e < 8; ++e) wv8[e] = weff[hgr * 16 + heh + e];
  const float c0 = weff[256];
  float sig_acc = 0.f;
  // ---- zero h8[0]; state
  for (int i = tid; i < 16 * 272 / 4; i += 512) ((unsigned*)h8[0])[i] = 0u;
  float c[2][4] = {{0.f, 0.f, 0.f, 0.f}, {0.f, 0.f, 0.f, 0.f}};
  float hv[2][4];
  float sHp = 0.f;  // scale of h in buffer 0 (zeros -> scale irrelevant)
  const unsigned short* gp = gx4 + ((((size_t)blk) * 8 + w) * 64 + (hi * 16 + lo)) * 32;
  unsigned GA[16], GB[16];
  {
    uint4 a = *(const uint4*)(gp);
    uint4 b = *(const uint4*)(gp + 8);
    uint4 c2 = *(const uint4*)(gp + 16);
    uint4 d2 = *(const uint4*)(gp + 24);
    GA[0] = a.x;  GA[1] = a.y;  GA[2] = a.z;  GA[3] = a.w;
    GA[4] = b.x;  GA[5] = b.y;  GA[6] = b.z;  GA[7] = b.w;
    GA[8] = c2.x; GA[9] = c2.y; GA[10] = c2.z; GA[11] = c2.w;
    GA[12] = d2.x; GA[13] = d2.y; GA[14] = d2.z; GA[15] = d2.w;
  }
  __syncthreads();

  auto step = [&](int t, unsigned (&Gc)[16], unsigned (&Gn)[16]) {
    const int cur = t & 1, nxt = cur ^ 1;
    // MFMA: K=256 in 4 chunks of 64; A = h8 frag, B = wq (same k recipe)
    i32x4 acc[4][2];
#pragma unroll
    for (int g = 0; g < 4; ++g)
#pragma unroll
      for (int t2 = 0; t2 < 2; ++t2) acc[g][t2] = (i32x4){0, 0, 0, 0};
#pragma unroll
    for (int kk = 0; kk < 4; ++kk) {
      i32x4 af = *(const i32x4*)&h8[cur][(kk * 4 + hi) * 272 + lo * 16];
#pragma unroll
      for (int g = 0; g < 4; ++g) {
        acc[g][0] = __builtin_amdgcn_mfma_i32_16x16x64_i8(af, wq[g][0][kk], acc[g][0], 0, 0, 0);
        acc[g][1] = __builtin_amdgcn_mfma_i32_16x16x64_i8(af, wq[g][1][kk], acc[g][1], 0, 0, 0);
      }
    }
    // issue gx(t+1) (only vmem in flight; full step to cover latency)
    if (t + 1 < TSTEPS) {
      const unsigned short* q = gp + (size_t)(t + 1) * 65536;
      uint4 a = *(const uint4*)(q);
      uint4 b = *(const uint4*)(q + 8);
      uint4 c2 = *(const uint4*)(q + 16);
      uint4 d2 = *(const uint4*)(q + 24);
      Gn[0] = a.x;  Gn[1] = a.y;  Gn[2] = a.z;  Gn[3] = a.w;
      Gn[4] = b.x;  Gn[5] = b.y;  Gn[6] = b.z;  Gn[7] = b.w;
      Gn[8] = c2.x; Gn[9] = c2.y; Gn[10] = c2.z; Gn[11] = c2.w;
      Gn[12] = d2.x; Gn[13] = d2.y; Gn[14] = d2.z; Gn[15] = d2.w;
    }
    // gates + cell update; lane owns (b = blk*16+hi*4+r, u = w*32+t2*16+lo)
    float scg[4][2];
#pragma unroll
    for (int g = 0; g < 4; ++g)
#pragma unroll
      for (int t2 = 0; t2 < 2; ++t2) scg[g][t2] = sW[g][t2] * sHp;
    float mx = 0.f;
#pragma unroll
    for (int t2 = 0; t2 < 2; ++t2)
#pragma unroll
      for (int r = 0; r < 4; ++r) {
        float gates[4];
#pragma unroll
        for (int g = 0; g < 4; ++g) {
          const int q = g * 2 + t2;
          unsigned word = Gc[q * 2 + (r >> 1)];
          unsigned short gv16 = (r & 1) ? (unsigned short)(word >> 16)
                                        : (unsigned short)word;
          gates[g] = bf2f(gv16) + (float)acc[g][t2][r] * scg[g][t2];
        }
        float iv = fsig(gates[0]), fv = fsig(gates[1]);
        float gg = ftanh(gates[2]), ov = fsig(gates[3]);
        c[t2][r] = fv * c[t2][r] + iv * gg;
        hv[t2][r] = ov * ftanh(c[t2][r]);
        mx = fmaxf(mx, fabsf(hv[t2][r]));
      }
    // block max |h| -> dynamic h scale
    mx = fmaxf(mx, __shfl_xor(mx, 1));  mx = fmaxf(mx, __shfl_xor(mx, 2));
    mx = fmaxf(mx, __shfl_xor(mx, 4));  mx = fmaxf(mx, __shfl_xor(mx, 8));
    mx = fmaxf(mx, __shfl_xor(mx, 16)); mx = fmaxf(mx, __shfl_xor(mx, 32));
    if (lane == 0) mxl[w] = mx;
    __syncthreads();                               // B1
    float bm = fmaxf(fmaxf(fmaxf(mxl[0], mxl[1]), fmaxf(mxl[2], mxl[3])),
                     fmaxf(fmaxf(mxl[4], mxl[5]), fmaxf(mxl[6], mxl[7])));
    bm = fmaxf(bm, 1e-8f);
    const float sHn = bm * (1.f / 127.f);
    const float rq = 127.f / bm;
#pragma unroll
    for (int t2 = 0; t2 < 2; ++t2)
#pragma unroll
      for (int r = 0; r < 4; ++r) {
        int qv = q8(hv[t2][r], rq);
        h8[nxt][(w * 2 + t2) * 272 + (hi * 4 + r) * 16 + lo] = (unsigned char)(qv & 255);
      }
    __syncthreads();                               // B2
    // fused head on h(t+1)
    {
      unsigned long long hb8 =
          *(const unsigned long long*)&h8[nxt][hgr * 272 + hb_b * 16 + heh];
      float s = 0.f;
#pragma unroll
      for (int e = 0; e < 8; ++e)
        s += (float)((signed char)(hb8 >> (8 * e))) * wv8[e];
      s *= sHn;
      s += __shfl_xor(s, 1);  s += __shfl_xor(s, 2);  s += __shfl_xor(s, 4);
      s += __shfl_xor(s, 8);  s += __shfl_xor(s, 16);
      sig_acc += fsig(s + c0);
    }
    sHp = sHn;
  };

  for (int t = 0; t < TSTEPS; t += 2) {
    step(t, GA, GB);
    step(t + 1, GB, GA);
  }
  // ---- epilogue
  if ((tid & 31) == 0) out[blk * 16 + hb_b] = sig_acc * (1.f / 512.f);
#pragma unroll
  for (int t2 = 0; t2 < 2; ++t2)
#pragma unroll
    for (int r = 0; r < 4; ++r) {
      const int b = blk * 16 + hi * 4 + r;
      const int u = w * 32 + t2 * 16 + lo;
      out[64 + b * HDIM + u] = hv[t2][r];
      out[64 + BATCH * HDIM + b * HDIM + u] = c[t2][r];
    }
}

// ---------------- K3: w_eff[k] = sum_j Wf[j]*Wm[j][k]; weff[256] = bm.Wf+bf --
__global__ __launch_bounds__(256) void k_weff(const float* __restrict__ Wm,
                                              const float* __restrict__ bm,
                                              const float* __restrict__ Wf,
                                              const float* __restrict__ bfb,
                                              float* __restrict__ weff) {
  const int k = threadIdx.x;
  __shared__ float red[256];
  float acc = 0.f;
#pragma unroll 8
  for (int jj = 0; jj < 256; ++jj) acc += Wf[jj] * Wm[jj * 256 + k];
  weff[k] = acc;
  red[k] = bm[k] * Wf[k];
  __syncthreads();
  for (int s = 128; s > 0; s >>= 1) {
    if (k < s) red[k] += red[k + s];
    __syncthreads();
  }
  if (k == 0) weff[256] = red[0] + bfb[0];
}

extern "C" void kernel_launch(void* const* d_in, const int* in_sizes, int n_in,
                              void* d_out, int out_size, void* d_ws, size_t ws_size,
                              hipStream_t stream) {
  (void)in_sizes; (void)n_in; (void)out_size; (void)ws_size;
  const int* x = (const int*)d_in[0];
  const float* emb = (const float*)d_in[1];
  const float* Wih = (const float*)d_in[2];
  const float* Whh = (const float*)d_in[3];
  const float* bih = (const float*)d_in[4];
  const float* bhh = (const float*)d_in[5];
  const float* Wm  = (const float*)d_in[6];
  const float* bm  = (const float*)d_in[7];
  const float* Wf  = (const float*)d_in[8];
  const float* bf  = (const float*)d_in[9];
  float* out = (float*)d_out;
  char* ws = (char*)d_ws;
  const size_t gx_bytes = (size_t)TSTEPS * BATCH * G4H * 2;  // 67,108,864
  unsigned short* gx4 = (unsigned short*)ws;
  float* weff = (float*)(ws + gx_bytes);
  k_gx<<<dim3(512, 16), 256, 0, stream>>>(x, emb, Wih, bih, bhh, gx4);
  k_weff<<<1, 256, 0, stream>>>(Wm, bm, Wf, bf, weff);
  k_rec<<<4, 512, 0, stream>>>(gx4, Whh, weff, out);
}